// Round 5
// baseline (780.243 us; speedup 1.0000x reference)
//
#include <hip/hip_runtime.h>

#define N_DIM 8192   // rows of features / columns of w / output length
#define K_DIM 512    // inner dim of features @ E
#define D_DIM 4096   // columns of E / rows of w

typedef __bf16 bf16x8 __attribute__((ext_vector_type(8)));
typedef float  f32x16 __attribute__((ext_vector_type(16)));
typedef unsigned short u16x8 __attribute__((ext_vector_type(8)));

__device__ __forceinline__ unsigned short f2bf(float f) {
    union { float f; unsigned int u; } v; v.f = f;
    unsigned int r = v.u + 0x7FFF + ((v.u >> 16) & 1);   // RNE
    return (unsigned short)(r >> 16);
}

// ---------------------------------------------------------------------------
// Kernel 1: E [512][4096] f32  ->  ET [4096][512] bf16 (k-contiguous rows)
// ---------------------------------------------------------------------------
__global__ __launch_bounds__(256) void transpose_E(const float* __restrict__ E,
                                                   unsigned short* __restrict__ ET) {
    __shared__ float tile[64][65];
    const int d0 = blockIdx.x * 64;
    const int k0 = blockIdx.y * 64;
    const int tid = threadIdx.x;
    const int r  = tid / 16;          // 0..15
    const int c4 = (tid % 16) * 4;    // 0..60
#pragma unroll
    for (int p = 0; p < 4; ++p) {
        int k = p * 16 + r;
        float4 v = *reinterpret_cast<const float4*>(E + (size_t)(k0 + k) * D_DIM + d0 + c4);
        tile[k][c4 + 0] = v.x; tile[k][c4 + 1] = v.y;
        tile[k][c4 + 2] = v.z; tile[k][c4 + 3] = v.w;
    }
    __syncthreads();
#pragma unroll
    for (int p = 0; p < 4; ++p) {
        int d = p * 16 + r;
        ushort4 o;
        o.x = f2bf(tile[c4 + 0][d]);
        o.y = f2bf(tile[c4 + 1][d]);
        o.z = f2bf(tile[c4 + 2][d]);
        o.w = f2bf(tile[c4 + 3][d]);
        *reinterpret_cast<ushort4*>(ET + (size_t)(d0 + d) * K_DIM + k0 + c4) = o;
    }
}

// ---------------------------------------------------------------------------
// Kernel 2: F [8192][512] f32 -> FB bf16 (k-contiguous rows).
// Blocks 0..7 also zero the 8192-float output.
// ---------------------------------------------------------------------------
__global__ __launch_bounds__(256) void convert_F(const float* __restrict__ F,
                                                 unsigned short* __restrict__ FB,
                                                 float* __restrict__ out) {
    if (blockIdx.x < 8) {
        float4 z = {0.f, 0.f, 0.f, 0.f};
        *reinterpret_cast<float4*>(out + (blockIdx.x * 256 + threadIdx.x) * 4) = z;
    }
    const int idx8 = (blockIdx.x * 256 + threadIdx.x) * 8;
    float4 a = *reinterpret_cast<const float4*>(F + idx8);
    float4 b = *reinterpret_cast<const float4*>(F + idx8 + 4);
    u16x8 o;
    o[0] = f2bf(a.x); o[1] = f2bf(a.y); o[2] = f2bf(a.z); o[3] = f2bf(a.w);
    o[4] = f2bf(b.x); o[5] = f2bf(b.y); o[6] = f2bf(b.z); o[7] = f2bf(b.w);
    *reinterpret_cast<u16x8*>(FB + idx8) = o;
}

// ---------------------------------------------------------------------------
// Kernel 3: fused  out[n] = sum_d (F@E + b)[n,d] * w[d,n], computed as y^T:
// Round 5: TILE SCALED to 256(d) x 256(n), BK=64, 8 waves (2d x 4n),
// 512 threads, single-buffered LDS (64 KB -> 2 blocks/CU), round-0/3's
// verified sync skeleton (stage -> vmcnt(0) -> barrier -> compute -> barrier).
// Rationale: 5 scheduling variants at 128^2 were all neutral; the invariants
// were tile geometry + LDS-read volume. 256^2 halves L2/HBM staging traffic
// (ET 64x->32x, FB 32x->16x reads), flips per-CU MFMA:LDS cycles from 1:1 to
// 1.33:1, and cuts barrier events 4x. XCD swizzle: each XCD owns a 4-tile
// n-band (1 MB FB hot in its L2) and sweeps d (ET streams, 256 KB hot),
// leaving ~2.5 MB L2 slack for the NT W stream.
// ---------------------------------------------------------------------------
__global__ __launch_bounds__(512, 4) void gemm_fused(const unsigned short* __restrict__ FB,
                                                     const float* __restrict__ W,
                                                     const unsigned short* __restrict__ ET,
                                                     const float* __restrict__ B,
                                                     float* __restrict__ out) {
    // [p-half][row 0..255][32 shorts]; p stride 8192 shorts (16 KB)
    __shared__ unsigned short Ash[2 * 256 * 32];  // ET tile: rows = d  (32 KB)
    __shared__ unsigned short Bsh[2 * 256 * 32];  // FB tile: rows = n  (32 KB)

    const int tid  = threadIdx.x;
    const int wave = tid >> 6;      // 0..7
    const int lane = tid & 63;
    const int wd   = wave >> 2;     // d-direction wave coord (0..1) -> 128 rows
    const int wn   = wave & 3;      // n-direction wave coord (0..3) -> 64 cols
    const int l31  = lane & 31;
    const int half = lane >> 5;

    // --- XCD swizzle: 512 blocks = 8 XCDs x 64. XCD owns n-band of 4 tiles,
    // sweeps d 0..15 (s>>2), cycling n within the band (s&3). Bijective.
    const int f   = blockIdx.x;
    const int xcd = f & 7;
    const int s   = f >> 3;               // 0..63
    const int ntile = xcd * 4 + (s & 3);  // 0..31
    const int dtile = s >> 2;             // 0..15
    const int n0 = ntile * 256;
    const int d0 = dtile * 256;

    f32x16 acc[4][2] = {};   // [mi=d-frag 0..3][ni=n-frag 0..1]

    // staging: one global_load_lds(16B) covers 16 rows x 64 B
    const int srow   = lane >> 2;                               // 0..15
    const int schunk = (((lane & 3) ^ ((srow >> 1) & 3)) * 8);  // swizzled chunk (shorts)

#pragma unroll
    for (int kt = 0; kt < K_DIM / 64; ++kt) {
        const int kb = kt * 64;
        // ---- stage: 8 waves x 2 j-groups cover 256 rows of A and B ----
#pragma unroll
        for (int p = 0; p < 2; ++p) {
#pragma unroll
            for (int jj = 0; jj < 2; ++jj) {
                const int j = wave * 2 + jj;   // 0..15 -> 16 rows each
                const unsigned short* ga =
                    ET + (size_t)(d0 + j * 16 + srow) * K_DIM + kb + p * 32 + schunk;
                __builtin_amdgcn_global_load_lds(
                    (const __attribute__((address_space(1))) void*)ga,
                    (__attribute__((address_space(3))) void*)(Ash + p * 8192 + j * 512),
                    16, 0, 0);
                const unsigned short* gb =
                    FB + (size_t)(n0 + j * 16 + srow) * K_DIM + kb + p * 32 + schunk;
                __builtin_amdgcn_global_load_lds(
                    (const __attribute__((address_space(1))) void*)gb,
                    (__attribute__((address_space(3))) void*)(Bsh + p * 8192 + j * 512),
                    16, 0, 0);
            }
        }
        asm volatile("s_waitcnt vmcnt(0)" ::: "memory");
        __builtin_amdgcn_sched_barrier(0);
        __builtin_amdgcn_s_barrier();
        __builtin_amdgcn_sched_barrier(0);

        // ---- compute: 4 ks x (4 A-frags + 2 B-frags) ds_read, 8 MFMA each ----
#pragma unroll
        for (int ks = 0; ks < 4; ++ks) {
            const int p = ks >> 1;
            const int c = (ks & 1) * 2 + half;   // 16B chunk index within 64B row
            bf16x8 af[4], bfr[2];
#pragma unroll
            for (int mi = 0; mi < 4; ++mi) {
                const int R = wd * 128 + mi * 32 + l31;
                const int slot = c ^ ((R >> 1) & 3);
                af[mi] = *reinterpret_cast<const bf16x8*>(
                    Ash + p * 8192 + R * 32 + slot * 8);
            }
#pragma unroll
            for (int ni = 0; ni < 2; ++ni) {
                const int R = wn * 64 + ni * 32 + l31;
                const int slot = c ^ ((R >> 1) & 3);
                bfr[ni] = *reinterpret_cast<const bf16x8*>(
                    Bsh + p * 8192 + R * 32 + slot * 8);
            }
#pragma unroll
            for (int mi = 0; mi < 4; ++mi)
#pragma unroll
                for (int ni = 0; ni < 2; ++ni)
                    acc[mi][ni] = __builtin_amdgcn_mfma_f32_32x32x16_bf16(
                        af[mi], bfr[ni], acc[mi][ni], 0, 0, 0);
        }

        // ---- LDS reuse barrier (next kt overwrites the single buffer) ----
        __builtin_amdgcn_sched_barrier(0);
        __builtin_amdgcn_s_barrier();
        __builtin_amdgcn_sched_barrier(0);
    }

    // --- epilogue: C layout 32x32: col(n)=lane&31, row(d)=(reg&3)+8*(reg>>2)+4*half
    // W read exactly once device-wide -> non-temporal scalar stream (proven
    // non-lever for scheduling across 5 experiments; cross-block overlap at
    // 2 blocks/CU hides the tail).
    const int nb = n0 + wn * 64;
    float part0 = 0.f, part1 = 0.f;
#pragma unroll
    for (int mi = 0; mi < 4; ++mi) {
        const int dbase = d0 + wd * 128 + mi * 32 + 4 * half;
#pragma unroll
        for (int reg = 0; reg < 16; ++reg) {
            const int dd = dbase + (reg & 3) + 8 * (reg >> 2);
            const float bd = B[dd];
            const float* wr = W + (size_t)dd * N_DIM + nb;
            part0 += (acc[mi][0][reg] + bd) * __builtin_nontemporal_load(wr + l31);
            part1 += (acc[mi][1][reg] + bd) * __builtin_nontemporal_load(wr + 32 + l31);
        }
    }
    part0 += __shfl_xor(part0, 32);
    part1 += __shfl_xor(part1, 32);
    if (lane < 32) {
        atomicAdd(out + nb + l31, part0);
        atomicAdd(out + nb + 32 + l31, part1);
    }
}

extern "C" void kernel_launch(void* const* d_in, const int* in_sizes, int n_in,
                              void* d_out, int out_size, void* d_ws, size_t ws_size,
                              hipStream_t stream) {
    const float* F = (const float*)d_in[0];   // features (N, K)
    const float* W = (const float*)d_in[1];   // w        (D, N)
    const float* E = (const float*)d_in[2];   // E        (K, D)
    const float* B = (const float*)d_in[3];   // b        (D,)
    float* out = (float*)d_out;               // (N,) f32

    unsigned short* ET = (unsigned short*)d_ws;                       // 4 MB
    unsigned short* FB = (unsigned short*)((char*)d_ws + (size_t)D_DIM * K_DIM * 2);  // 8 MB

    transpose_E<<<dim3(D_DIM / 64, K_DIM / 64), 256, 0, stream>>>(E, ET);
    convert_F<<<dim3(N_DIM * K_DIM / (256 * 8)), 256, 0, stream>>>(F, FB, out);
    gemm_fused<<<dim3((N_DIM / 256) * (D_DIM / 256)), 512, 0, stream>>>(FB, W, ET, B, out);
}

// Round 6
// 232.309 us; speedup vs baseline: 3.3586x; 3.3586x over previous
//
#include <hip/hip_runtime.h>

#define N_DIM 8192   // rows of features / columns of w / output length
#define K_DIM 512    // inner dim of features @ E
#define D_DIM 4096   // columns of E / rows of w

typedef __bf16 bf16x8 __attribute__((ext_vector_type(8)));
typedef float  f32x16 __attribute__((ext_vector_type(16)));
typedef unsigned short u16x8 __attribute__((ext_vector_type(8)));

__device__ __forceinline__ unsigned short f2bf(float f) {
    union { float f; unsigned int u; } v; v.f = f;
    unsigned int r = v.u + 0x7FFF + ((v.u >> 16) & 1);   // RNE
    return (unsigned short)(r >> 16);
}

// ---------------------------------------------------------------------------
// Kernel 1: E [512][4096] f32  ->  ET [4096][512] bf16 (k-contiguous rows)
// ---------------------------------------------------------------------------
__global__ __launch_bounds__(256) void transpose_E(const float* __restrict__ E,
                                                   unsigned short* __restrict__ ET) {
    __shared__ float tile[64][65];
    const int d0 = blockIdx.x * 64;
    const int k0 = blockIdx.y * 64;
    const int tid = threadIdx.x;
    const int r  = tid / 16;          // 0..15
    const int c4 = (tid % 16) * 4;    // 0..60
#pragma unroll
    for (int p = 0; p < 4; ++p) {
        int k = p * 16 + r;
        float4 v = *reinterpret_cast<const float4*>(E + (size_t)(k0 + k) * D_DIM + d0 + c4);
        tile[k][c4 + 0] = v.x; tile[k][c4 + 1] = v.y;
        tile[k][c4 + 2] = v.z; tile[k][c4 + 3] = v.w;
    }
    __syncthreads();
#pragma unroll
    for (int p = 0; p < 4; ++p) {
        int d = p * 16 + r;
        ushort4 o;
        o.x = f2bf(tile[c4 + 0][d]);
        o.y = f2bf(tile[c4 + 1][d]);
        o.z = f2bf(tile[c4 + 2][d]);
        o.w = f2bf(tile[c4 + 3][d]);
        *reinterpret_cast<ushort4*>(ET + (size_t)(d0 + d) * K_DIM + k0 + c4) = o;
    }
}

// ---------------------------------------------------------------------------
// Kernel 2: F [8192][512] f32 -> FB bf16 (k-contiguous rows).
// Blocks 0..7 also zero the 8192-float output (replaces memset dispatch).
// ---------------------------------------------------------------------------
__global__ __launch_bounds__(256) void convert_F(const float* __restrict__ F,
                                                 unsigned short* __restrict__ FB,
                                                 float* __restrict__ out) {
    if (blockIdx.x < 8) {
        float4 z = {0.f, 0.f, 0.f, 0.f};
        *reinterpret_cast<float4*>(out + (blockIdx.x * 256 + threadIdx.x) * 4) = z;
    }
    const int idx8 = (blockIdx.x * 256 + threadIdx.x) * 8;
    float4 a = *reinterpret_cast<const float4*>(F + idx8);
    float4 b = *reinterpret_cast<const float4*>(F + idx8 + 4);
    u16x8 o;
    o[0] = f2bf(a.x); o[1] = f2bf(a.y); o[2] = f2bf(a.z); o[3] = f2bf(a.w);
    o[4] = f2bf(b.x); o[5] = f2bf(b.y); o[6] = f2bf(b.z); o[7] = f2bf(b.w);
    *reinterpret_cast<u16x8*>(FB + idx8) = o;
}

// ---------------------------------------------------------------------------
// Kernel 3: fused  out[n] = sum_d (F@E + b)[n,d] * w[d,n], computed as y^T:
// C-tile 128(d) x 128(n), BK=64, 4 waves (2x2), 32x32x16 bf16 MFMA.
// Round 6: round-0 structure EXACTLY, occupancy 2 -> 3 blocks/CU.
//   - R5's spill counters exposed the mechanism: acc=64 AGPR + fully-unrolled
//     kt address-hoisting (~164 arch regs, m97 precedent) = ~228 total ->
//     round-0's (256,2) bound ran at 2 blocks/CU only.
//   - #pragma unroll 1 on kt: addresses recomputed per iteration, arch regs
//     ~70-80, total ~150 -> fits __launch_bounds__(256,3) cap (~168) without
//     spill -> 3 blocks/CU (96 KB LDS, 12 waves/CU = m97's measured regime).
//   - 3 anti-phased blocks hide stage-drain + each other's W-epilogue tails
//     (the m114 cross-block mechanism the five neutral scheduling variants
//     could never access at 2 blocks).
// ---------------------------------------------------------------------------
__global__ __launch_bounds__(256, 3) void gemm_fused(const unsigned short* __restrict__ FB,
                                                     const float* __restrict__ W,
                                                     const unsigned short* __restrict__ ET,
                                                     const float* __restrict__ B,
                                                     float* __restrict__ out) {
    __shared__ unsigned short Ash[2 * 128 * 32];  // ET tile: rows = d (16 KB)
    __shared__ unsigned short Bsh[2 * 128 * 32];  // FB tile: rows = n (16 KB)

    const int tid  = threadIdx.x;
    const int wave = tid >> 6;
    const int lane = tid & 63;
    const int wy   = wave >> 1;     // d-direction wave coord (0..1)
    const int wx   = wave & 1;      // n-direction wave coord (0..1)
    const int l31  = lane & 31;
    const int half = lane >> 5;

    // --- XCD-rectangle swizzle (bijection on 64x32 grid) ---
    const int f   = blockIdx.x + ((int)gridDim.x) * blockIdx.y;  // dispatch order
    const int xcd = f & 7;
    const int s   = f >> 3;               // 0..255 within XCD
    const int ntile = (xcd & 3) * 16 + (s & 15);   // 0..63
    const int dtile = (xcd >> 2) * 16 + (s >> 4);  // 0..31
    const int n0 = ntile * 128;
    const int d0 = dtile * 128;

    f32x16 acc[2][2] = {};   // [mi=d-tile][ni=n-tile]

    // staging: one global_load_lds(16B) covers 16 rows x 64 B
    const int srow   = lane >> 2;                               // 0..15
    const int schunk = (((lane & 3) ^ ((srow >> 1) & 3)) * 8);  // swizzled chunk (shorts)

#pragma unroll 1   // rolled: keep live address ranges small (reg cap 168)
    for (int kt = 0; kt < K_DIM / 64; ++kt) {
        const int kb = kt * 64;
#pragma unroll
        for (int p = 0; p < 2; ++p) {
#pragma unroll
            for (int jj = 0; jj < 2; ++jj) {
                const int j = wave * 2 + jj;   // 0..7 -> 16 rows each
                const unsigned short* ga =
                    ET + (size_t)(d0 + j * 16 + srow) * K_DIM + kb + p * 32 + schunk;
                __builtin_amdgcn_global_load_lds(
                    (const __attribute__((address_space(1))) void*)ga,
                    (__attribute__((address_space(3))) void*)(Ash + p * 4096 + j * 512),
                    16, 0, 0);
                const unsigned short* gb =
                    FB + (size_t)(n0 + j * 16 + srow) * K_DIM + kb + p * 32 + schunk;
                __builtin_amdgcn_global_load_lds(
                    (const __attribute__((address_space(1))) void*)gb,
                    (__attribute__((address_space(3))) void*)(Bsh + p * 4096 + j * 512),
                    16, 0, 0);
            }
        }
        __syncthreads();

#pragma unroll
        for (int ks = 0; ks < 4; ++ks) {
            const int p = ks >> 1;
            const int c = (ks & 1) * 2 + half;   // 16B chunk index within row
            bf16x8 af[2], bfr[2];
#pragma unroll
            for (int mi = 0; mi < 2; ++mi) {
                const int R = wy * 64 + mi * 32 + l31;
                const int slot = c ^ ((R >> 1) & 3);
                af[mi] = *reinterpret_cast<const bf16x8*>(
                    Ash + p * 4096 + R * 32 + slot * 8);
            }
#pragma unroll
            for (int ni = 0; ni < 2; ++ni) {
                const int R = wx * 64 + ni * 32 + l31;
                const int slot = c ^ ((R >> 1) & 3);
                bfr[ni] = *reinterpret_cast<const bf16x8*>(
                    Bsh + p * 4096 + R * 32 + slot * 8);
            }
#pragma unroll
            for (int mi = 0; mi < 2; ++mi)
#pragma unroll
                for (int ni = 0; ni < 2; ++ni)
                    acc[mi][ni] = __builtin_amdgcn_mfma_f32_32x32x16_bf16(
                        af[mi], bfr[ni], acc[mi][ni], 0, 0, 0);
        }
        __syncthreads();
    }

    // --- epilogue: C layout 32x32: col(n)=lane&31, row(d)=(reg&3)+8*(reg>>2)+4*half
    // W is read exactly once device-wide -> non-temporal (don't evict L2 tiles)
    const int nb = n0 + wx * 64;
    float part0 = 0.f, part1 = 0.f;
#pragma unroll
    for (int mi = 0; mi < 2; ++mi) {
        const int dbase = d0 + wy * 64 + mi * 32 + 4 * half;
#pragma unroll
        for (int reg = 0; reg < 16; ++reg) {
            const int dd = dbase + (reg & 3) + 8 * (reg >> 2);
            const float bd = B[dd];
            const float* wr = W + (size_t)dd * N_DIM + nb;
            part0 += (acc[mi][0][reg] + bd) * __builtin_nontemporal_load(wr + l31);
            part1 += (acc[mi][1][reg] + bd) * __builtin_nontemporal_load(wr + 32 + l31);
        }
    }
    part0 += __shfl_xor(part0, 32);
    part1 += __shfl_xor(part1, 32);
    if (lane < 32) {
        atomicAdd(out + nb + l31, part0);
        atomicAdd(out + nb + 32 + l31, part1);
    }
}

extern "C" void kernel_launch(void* const* d_in, const int* in_sizes, int n_in,
                              void* d_out, int out_size, void* d_ws, size_t ws_size,
                              hipStream_t stream) {
    const float* F = (const float*)d_in[0];   // features (N, K)
    const float* W = (const float*)d_in[1];   // w        (D, N)
    const float* E = (const float*)d_in[2];   // E        (K, D)
    const float* B = (const float*)d_in[3];   // b        (D,)
    float* out = (float*)d_out;               // (N,) f32

    unsigned short* ET = (unsigned short*)d_ws;                       // 4 MB
    unsigned short* FB = (unsigned short*)((char*)d_ws + (size_t)D_DIM * K_DIM * 2);  // 8 MB

    transpose_E<<<dim3(D_DIM / 64, K_DIM / 64), 256, 0, stream>>>(E, ET);
    convert_F<<<dim3(N_DIM * K_DIM / (256 * 8)), 256, 0, stream>>>(F, FB, out);
    gemm_fused<<<dim3(N_DIM / 128, D_DIM / 128), 256, 0, stream>>>(FB, W, ET, B, out);
}

// Round 7
// 231.306 us; speedup vs baseline: 3.3732x; 1.0043x over previous
//
#include <hip/hip_runtime.h>

#define N_DIM 8192   // rows of features / columns of w / output length
#define K_DIM 512    // inner dim of features @ E
#define D_DIM 4096   // columns of E / rows of w

typedef __bf16 bf16x8 __attribute__((ext_vector_type(8)));
typedef float  f32x16 __attribute__((ext_vector_type(16)));
typedef unsigned short u16x8 __attribute__((ext_vector_type(8)));

__device__ __forceinline__ unsigned short f2bf(float f) {
    union { float f; unsigned int u; } v; v.f = f;
    unsigned int r = v.u + 0x7FFF + ((v.u >> 16) & 1);   // RNE
    return (unsigned short)(r >> 16);
}

// ---------------------------------------------------------------------------
// Kernel 1: E [512][4096] f32  ->  ET [4096][512] bf16 (k-contiguous rows)
// ---------------------------------------------------------------------------
__global__ __launch_bounds__(256) void transpose_E(const float* __restrict__ E,
                                                   unsigned short* __restrict__ ET) {
    __shared__ float tile[64][65];
    const int d0 = blockIdx.x * 64;
    const int k0 = blockIdx.y * 64;
    const int tid = threadIdx.x;
    const int r  = tid / 16;          // 0..15
    const int c4 = (tid % 16) * 4;    // 0..60
#pragma unroll
    for (int p = 0; p < 4; ++p) {
        int k = p * 16 + r;
        float4 v = *reinterpret_cast<const float4*>(E + (size_t)(k0 + k) * D_DIM + d0 + c4);
        tile[k][c4 + 0] = v.x; tile[k][c4 + 1] = v.y;
        tile[k][c4 + 2] = v.z; tile[k][c4 + 3] = v.w;
    }
    __syncthreads();
#pragma unroll
    for (int p = 0; p < 4; ++p) {
        int d = p * 16 + r;
        ushort4 o;
        o.x = f2bf(tile[c4 + 0][d]);
        o.y = f2bf(tile[c4 + 1][d]);
        o.z = f2bf(tile[c4 + 2][d]);
        o.w = f2bf(tile[c4 + 3][d]);
        *reinterpret_cast<ushort4*>(ET + (size_t)(d0 + d) * K_DIM + k0 + c4) = o;
    }
}

// ---------------------------------------------------------------------------
// Kernel 2: F [8192][512] f32 -> FB bf16 (k-contiguous rows).
// Blocks 0..7 also zero the 8192-float output (replaces memset dispatch).
// ---------------------------------------------------------------------------
__global__ __launch_bounds__(256) void convert_F(const float* __restrict__ F,
                                                 unsigned short* __restrict__ FB,
                                                 float* __restrict__ out) {
    if (blockIdx.x < 8) {
        float4 z = {0.f, 0.f, 0.f, 0.f};
        *reinterpret_cast<float4*>(out + (blockIdx.x * 256 + threadIdx.x) * 4) = z;
    }
    const int idx8 = (blockIdx.x * 256 + threadIdx.x) * 8;
    float4 a = *reinterpret_cast<const float4*>(F + idx8);
    float4 b = *reinterpret_cast<const float4*>(F + idx8 + 4);
    u16x8 o;
    o[0] = f2bf(a.x); o[1] = f2bf(a.y); o[2] = f2bf(a.z); o[3] = f2bf(a.w);
    o[4] = f2bf(b.x); o[5] = f2bf(b.y); o[6] = f2bf(b.z); o[7] = f2bf(b.w);
    *reinterpret_cast<u16x8*>(FB + idx8) = o;
}

// ---------------------------------------------------------------------------
// Kernel 3: fused  out[n] = sum_d (F@E + b)[n,d] * w[d,n], computed as y^T.
// Round 7: RATIO TILE 128(d) x 256(n), BK=64, 4 waves (2x2), each wave owns
// 64d x 128n -> acc[2][4] (128 VGPR). Per ks: 6 ds_read_b128 feed 8 MFMA
// (0.75 KB LDS / 8-cyc MFMA, 25% under the 128 B/cyc LDS ceiling; 64 cyc of
// MFMA covers ds_read latency, 2x round-6). All schedule variants at the
// 1:1-ratio 128^2 tile were neutral -- the geometry, not the schedule, was
// binding. ~200 VGPR at (256,2): no spill (R5's failure mode excluded),
// 2 blocks/CU, LDS 48 KB/block. Staging L2 traffic 512->384 MB. Sync
// skeleton, staging swizzle, NT W epilogue: proven R0/R6 code verbatim.
// ---------------------------------------------------------------------------
__global__ __launch_bounds__(256, 2) void gemm_fused(const unsigned short* __restrict__ FB,
                                                     const float* __restrict__ W,
                                                     const unsigned short* __restrict__ ET,
                                                     const float* __restrict__ B,
                                                     float* __restrict__ out) {
    __shared__ unsigned short Ash[2 * 128 * 32];  // ET tile: 128 d-rows (16 KB)
    __shared__ unsigned short Bsh[2 * 256 * 32];  // FB tile: 256 n-rows (32 KB)

    const int tid  = threadIdx.x;
    const int wave = tid >> 6;
    const int lane = tid & 63;
    const int wy   = wave >> 1;     // d-direction wave coord (0..1) -> 64 rows
    const int wx   = wave & 1;      // n-direction wave coord (0..1) -> 128 cols
    const int l31  = lane & 31;
    const int half = lane >> 5;

    // --- XCD swizzle: 1024 blocks = 8 XCDs x 128. Each XCD owns a 4-tile
    // n-band (1 MB FB hot in its L2), sweeps d. Bijective.
    const int f   = blockIdx.x;
    const int xcd = f & 7;
    const int s   = f >> 3;               // 0..127
    const int ntile = xcd * 4 + (s & 3);  // 0..31
    const int dtile = s >> 2;             // 0..31
    const int n0 = ntile * 256;
    const int d0 = dtile * 128;

    f32x16 acc[2][4] = {};   // [mi=d-frag][ni=n-frag]

    // staging: one global_load_lds(16B) covers 16 rows x 64 B
    const int srow   = lane >> 2;                               // 0..15
    const int schunk = (((lane & 3) ^ ((srow >> 1) & 3)) * 8);  // swizzled chunk (shorts)

#pragma unroll 1   // rolled kt: keep live address ranges small (reg cap 256)
    for (int kt = 0; kt < K_DIM / 64; ++kt) {
        const int kb = kt * 64;
#pragma unroll
        for (int p = 0; p < 2; ++p) {
            // A: 8 groups x 16 d-rows (2 per wave)
#pragma unroll
            for (int jj = 0; jj < 2; ++jj) {
                const int j = wave * 2 + jj;   // 0..7
                const unsigned short* ga =
                    ET + (size_t)(d0 + j * 16 + srow) * K_DIM + kb + p * 32 + schunk;
                __builtin_amdgcn_global_load_lds(
                    (const __attribute__((address_space(1))) void*)ga,
                    (__attribute__((address_space(3))) void*)(Ash + p * 4096 + j * 512),
                    16, 0, 0);
            }
            // B: 16 groups x 16 n-rows (4 per wave)
#pragma unroll
            for (int jj = 0; jj < 4; ++jj) {
                const int j = wave * 4 + jj;   // 0..15
                const unsigned short* gb =
                    FB + (size_t)(n0 + j * 16 + srow) * K_DIM + kb + p * 32 + schunk;
                __builtin_amdgcn_global_load_lds(
                    (const __attribute__((address_space(1))) void*)gb,
                    (__attribute__((address_space(3))) void*)(Bsh + p * 8192 + j * 512),
                    16, 0, 0);
            }
        }
        __syncthreads();

#pragma unroll
        for (int ks = 0; ks < 4; ++ks) {
            const int p = ks >> 1;
            const int c = (ks & 1) * 2 + half;   // 16B chunk index within 64B row
            bf16x8 af[2], bfr[4];
#pragma unroll
            for (int mi = 0; mi < 2; ++mi) {
                const int R = wy * 64 + mi * 32 + l31;
                const int slot = c ^ ((R >> 1) & 3);
                af[mi] = *reinterpret_cast<const bf16x8*>(
                    Ash + p * 4096 + R * 32 + slot * 8);
            }
#pragma unroll
            for (int ni = 0; ni < 4; ++ni) {
                const int R = wx * 128 + ni * 32 + l31;
                const int slot = c ^ ((R >> 1) & 3);
                bfr[ni] = *reinterpret_cast<const bf16x8*>(
                    Bsh + p * 8192 + R * 32 + slot * 8);
            }
#pragma unroll
            for (int mi = 0; mi < 2; ++mi)
#pragma unroll
                for (int ni = 0; ni < 4; ++ni)
                    acc[mi][ni] = __builtin_amdgcn_mfma_f32_32x32x16_bf16(
                        af[mi], bfr[ni], acc[mi][ni], 0, 0, 0);
        }
        __syncthreads();
    }

    // --- epilogue: C layout 32x32: col(n)=lane&31, row(d)=(reg&3)+8*(reg>>2)+4*half
    // W read exactly once device-wide -> non-temporal scalar stream.
    const int nbase = n0 + wx * 128;
    float part0 = 0.f, part1 = 0.f, part2 = 0.f, part3 = 0.f;
#pragma unroll
    for (int mi = 0; mi < 2; ++mi) {
        const int dbase = d0 + wy * 64 + mi * 32 + 4 * half;
#pragma unroll
        for (int reg = 0; reg < 16; ++reg) {
            const int dd = dbase + (reg & 3) + 8 * (reg >> 2);
            const float bd = B[dd];
            const float* wr = W + (size_t)dd * N_DIM + nbase;
            part0 += (acc[mi][0][reg] + bd) * __builtin_nontemporal_load(wr + l31);
            part1 += (acc[mi][1][reg] + bd) * __builtin_nontemporal_load(wr + 32 + l31);
            part2 += (acc[mi][2][reg] + bd) * __builtin_nontemporal_load(wr + 64 + l31);
            part3 += (acc[mi][3][reg] + bd) * __builtin_nontemporal_load(wr + 96 + l31);
        }
    }
    part0 += __shfl_xor(part0, 32);
    part1 += __shfl_xor(part1, 32);
    part2 += __shfl_xor(part2, 32);
    part3 += __shfl_xor(part3, 32);
    if (lane < 32) {
        atomicAdd(out + nbase + l31, part0);
        atomicAdd(out + nbase + 32 + l31, part1);
        atomicAdd(out + nbase + 64 + l31, part2);
        atomicAdd(out + nbase + 96 + l31, part3);
    }
}

extern "C" void kernel_launch(void* const* d_in, const int* in_sizes, int n_in,
                              void* d_out, int out_size, void* d_ws, size_t ws_size,
                              hipStream_t stream) {
    const float* F = (const float*)d_in[0];   // features (N, K)
    const float* W = (const float*)d_in[1];   // w        (D, N)
    const float* E = (const float*)d_in[2];   // E        (K, D)
    const float* B = (const float*)d_in[3];   // b        (D,)
    float* out = (float*)d_out;               // (N,) f32

    unsigned short* ET = (unsigned short*)d_ws;                       // 4 MB
    unsigned short* FB = (unsigned short*)((char*)d_ws + (size_t)D_DIM * K_DIM * 2);  // 8 MB

    transpose_E<<<dim3(D_DIM / 64, K_DIM / 64), 256, 0, stream>>>(E, ET);
    convert_F<<<dim3(N_DIM * K_DIM / (256 * 8)), 256, 0, stream>>>(F, FB, out);
    gemm_fused<<<dim3((N_DIM / 256) * (D_DIM / 128)), 256, 0, stream>>>(FB, W, ET, B, out);
}